// Round 19
// baseline (101.230 us; speedup 1.0000x reference)
//
#include <hip/hip_runtime.h>

typedef __attribute__((ext_vector_type(8))) short short8;
typedef __attribute__((ext_vector_type(4))) float f32x4;

constexpr int H = 512, W = 512;
constexpr int P = H * W;     // 262144
constexpr int NSP = 1024;
constexpr int SBLK = 512;    // scatter partial sets
constexpr int FGRP = 16;     // finalize stage-A groups (32 sets each)

__device__ inline unsigned short f2bf(float f) {
  unsigned u = __builtin_bit_cast(unsigned, f);
  unsigned r = (u + 0x7fffu + ((u >> 16) & 1u)) >> 16;  // RNE
  return (unsigned short)r;
}
__device__ inline float bflo(unsigned u) { return __builtin_bit_cast(float, u << 16); }
__device__ inline float bfhi(unsigned u) { return __builtin_bit_cast(float, u & 0xffff0000u); }

// XCD-band swizzle (bijective: grid % 8 == 0). cpx = grid/8.
__device__ inline int xcd_swz(int b, int cpx) { return (b & 7) * cpx + (b >> 3); }

// ---------------- prep: weights -> [chunk][row][slot][8] bf16 (plain order) ----------------
// Reader (global 16B loads): af(k, r, q) at  k*CS + r*32 + q*8  shorts.
__global__ __launch_bounds__(256) void prep_k(const float* __restrict__ w2,
                                              const float* __restrict__ w3,
                                              unsigned short* __restrict__ wt2s,
                                              unsigned short* __restrict__ wt3s,
                                              unsigned short* __restrict__ zeros) {
  if (blockIdx.x == 0 && threadIdx.x < 128) zeros[threadIdx.x] = 0;  // 256-B zero stub
  int i = blockIdx.x * 256 + threadIdx.x;
  if (i < 36864) {                     // conv2: 18 chunks x 2048 shorts (64 oc rows)
    int k = i >> 11;
    int t = (i >> 3) & 255;
    int e = i & 7;
    int r = t >> 2, s = t & 3;
    int tap = k >> 1, ic = (k & 1) * 32 + s * 8 + e;
    wt2s[i] = f2bf(w2[r * 576 + ic * 9 + tap]);
  } else if (i < 46080) {              // conv3: 18 chunks x 512 shorts (16 rows, 10 real)
    int j = i - 36864;
    int k = j >> 9;
    int t = (j >> 3) & 63;
    int e = j & 7;
    int r = t >> 2, s = t & 3;
    int tap = k >> 1, ic = (k & 1) * 32 + s * 8 + e;
    wt3s[j] = (r < 10) ? f2bf(w3[r * 576 + ic * 9 + tap]) : (unsigned short)0;
  }
}

// ---------------- conv2 (fused conv1-via-MFMA + conv2): raw -> h2 NHWC bf16; 32x8, 512 thr ----------------
// Phase 2 is BARRIER-FREE: A-frags read straight from L2 (coalesced 1KB/wave),
// acts LDS read-only. LDS 45.9 KB -> 3 blk/CU.
__global__ __launch_bounds__(512, 6) void conv2_k(const float* __restrict__ raw,
                                                  const float* __restrict__ w1,
                                                  const float* __restrict__ b1,
                                                  const unsigned short* __restrict__ wts,
                                                  const float* __restrict__ bias,
                                                  unsigned short* __restrict__ ynhwc) {
  __shared__ __align__(16) unsigned short acts[352 * 64];  // 45056 B
  __shared__ unsigned short rawtb[12 * 36 + 4];            // 872 B => 45928 B, 3 blk/CU
  int tid = threadIdx.x;
  int lane = tid & 63, wave = tid >> 6;                    // 8 waves
  int logical = xcd_swz(blockIdx.x, 128);
  int tilex = logical & 15, tiley = logical >> 4;
  int c0 = tilex * 32, r0 = tiley * 8;

  // ---- stage raw halo-of-halo [12 rows][36 cols] (rows r0-2 .. r0+9) as bf16 ----
  if (tid < 432) {
    int rr = tid / 36, cc = tid - rr * 36;
    int gr = r0 + rr - 2, gc = c0 + cc - 2;
    bool ok = ((unsigned)gr < 512u) && ((unsigned)gc < 512u);
    rawtb[tid] = ok ? f2bf(raw[gr * 512 + gc]) : (unsigned short)0;
  }

  int q = lane >> 4, n = lane & 15;
  int og1 = wave & 3;
  // A-frag for conv1: row = oc (og1*16+n), k = q*8+e; taps 0-8 real, rest 0.
  short8 a1f;
  {
    short av[8];
#pragma unroll
    for (int e = 0; e < 8; ++e) av[e] = 0;
    int oc = og1 * 16 + n;
    if (q == 0) {
#pragma unroll
      for (int e = 0; e < 8; ++e) av[e] = (short)f2bf(w1[oc * 9 + e]);
    } else if (q == 1) {
      av[0] = (short)f2bf(w1[oc * 9 + 8]);
    }
    a1f = (short8){av[0], av[1], av[2], av[3], av[4], av[5], av[6], av[7]};
  }
  float bb1[4];
#pragma unroll
  for (int r2 = 0; r2 < 4; ++r2) bb1[r2] = b1[og1 * 16 + q * 4 + r2];
  __syncthreads();  // rawtb visible

  // ---- phase 1: conv1 via MFMA; waves 0-3: t=0..10, waves 4-7: t=11..21 ----
  char* actw = (char*)acts;
  int tbase = (wave < 4) ? 0 : 11;
  for (int ti = 0; ti < 11; ++ti) {
    int t = tbase + ti;
    int px = t * 16 + n;                                 // 0..351
    bool okp = px < 340;
    int prow = px / 34, pcol = px - prow * 34;
    int prc = okp ? prow : 9;                            // clamp rawtb row for px>=340
    short bv[8];
#pragma unroll
    for (int e = 0; e < 8; ++e) bv[e] = 0;
    if (q == 0) {
#pragma unroll
      for (int e = 0; e < 8; ++e) {
        int dy = e / 3, dx = e - dy * 3;                 // taps 0..7
        bv[e] = (short)rawtb[(prc + dy) * 36 + pcol + dx];
      }
    } else if (q == 1) {
      bv[0] = (short)rawtb[(prc + 2) * 36 + pcol + 2];   // tap 8
    }
    short8 b1f = (short8){bv[0], bv[1], bv[2], bv[3], bv[4], bv[5], bv[6], bv[7]};
    f32x4 d = __builtin_amdgcn_mfma_f32_16x16x32_bf16(a1f, b1f,
                                                       (f32x4){0.f, 0.f, 0.f, 0.f}, 0, 0, 0);
    int gr1 = r0 + prow - 1, gc1 = c0 + pcol - 1;
    bool ok1 = okp && ((unsigned)gr1 < 512u) && ((unsigned)gc1 < 512u);
    float o0 = ok1 ? fmaxf(d.x + bb1[0], 0.f) : 0.f;
    float o1 = ok1 ? fmaxf(d.y + bb1[1], 0.f) : 0.f;
    float o2 = ok1 ? fmaxf(d.z + bb1[2], 0.f) : 0.f;
    float o3 = ok1 ? fmaxf(d.w + bb1[3], 0.f) : 0.f;
    unsigned lo = (unsigned)f2bf(o0) | ((unsigned)f2bf(o1) << 16);
    unsigned hi = (unsigned)f2bf(o2) | ((unsigned)f2bf(o3) << 16);
    int wa = px * 128 + ((((og1 * 2 + (q >> 1)) ^ (px & 7)) << 4)) + ((q & 1) << 3);
    *reinterpret_cast<uint2*>(actw + wa) = make_uint2(lo, hi);
  }
  __syncthreads();  // acts complete

  // ---- phase 2: barrier-free; af from global (L2), bf from acts LDS ----
  f32x4 acc[4][2];
#pragma unroll
  for (int og = 0; og < 4; ++og)
#pragma unroll
    for (int g = 0; g < 2; ++g) acc[og][g] = (f32x4){0.f, 0.f, 0.f, 0.f};

  int plbase[2];
#pragma unroll
  for (int g = 0; g < 2; ++g) plbase[g] = wave * 34 + 16 * g + n;
  const char* actb = (const char*)acts;

#pragma unroll
  for (int j = 0; j < 9; ++j) {
    const int kyy = j / 3, kxx = j - kyy * 3;
#pragma unroll
    for (int kc = 0; kc < 2; ++kc) {
      const int k = j * 2 + kc;
      short8 af[4];
#pragma unroll
      for (int og = 0; og < 4; ++og) {
        const unsigned short* ap = wts + (size_t)k * 2048 + (og * 16 + n) * 32 + q * 8;
        af[og] = *reinterpret_cast<const short8*>(ap);
      }
#pragma unroll
      for (int g = 0; g < 2; ++g) {
        int pl = plbase[g] + kyy * 34 + kxx;
        int addr = pl * 128 + (((kc * 4 + q) ^ (pl & 7)) * 16);
        short8 bf = *reinterpret_cast<const short8*>(actb + addr);
#pragma unroll
        for (int og = 0; og < 4; ++og)
          acc[og][g] = __builtin_amdgcn_mfma_f32_16x16x32_bf16(af[og], bf, acc[og][g], 0, 0, 0);
      }
    }
  }

  // ---- epilogue: acc -> LDS (swizzled NHWC tile, 256 px) -> coalesced 16B stores ----
  __syncthreads();  // acts reads done; safe to reuse as output staging
  char* ob = (char*)acts;
#pragma unroll
  for (int og = 0; og < 4; ++og) {
    float b0 = bias[og * 16 + q * 4 + 0], b1v = bias[og * 16 + q * 4 + 1];
    float b2 = bias[og * 16 + q * 4 + 2], b3 = bias[og * 16 + q * 4 + 3];
#pragma unroll
    for (int g = 0; g < 2; ++g) {
      int pl = wave * 32 + g * 16 + n;
      f32x4 v = acc[og][g];
      float o0 = fmaxf(v.x + b0, 0.f), o1 = fmaxf(v.y + b1v, 0.f);
      float o2 = fmaxf(v.z + b2, 0.f), o3 = fmaxf(v.w + b3, 0.f);
      unsigned lo = (unsigned)f2bf(o0) | ((unsigned)f2bf(o1) << 16);
      unsigned hi = (unsigned)f2bf(o2) | ((unsigned)f2bf(o3) << 16);
      int lslot = og * 2 + (q >> 1);                   // logical 16B slot
      int wa = pl * 128 + (((lslot ^ (pl & 7)) << 4)) + ((q & 1) << 3);
      *reinterpret_cast<uint2*>(ob + wa) = make_uint2(lo, hi);
    }
  }
  __syncthreads();
  char* yb = (char*)ynhwc;
#pragma unroll
  for (int it = 0; it < 4; ++it) {
    int c = it * 512 + tid;                            // 2048 16-B chunks
    int pl = c >> 3, slot = c & 7;
    uint4 v = *reinterpret_cast<const uint4*>(ob + pl * 128 + ((slot ^ (pl & 7)) << 4));
    size_t gb = (((size_t)(r0 + (pl >> 5)) * 512) + c0 + (pl & 31)) * 128 + slot * 16;
    *reinterpret_cast<uint4*>(yb + gb) = v;
  }
}

// ---------------- conv3 (MFMA): 64 -> 10, NHWC bf16 out; 32x8, 512 thr; af from L2 ----------------
__global__ __launch_bounds__(512, 6) void conv3_k(const unsigned short* __restrict__ xin,
                                                  const unsigned short* __restrict__ wts,
                                                  const float* __restrict__ bias,
                                                  unsigned short* __restrict__ feats,
                                                  const unsigned short* __restrict__ zeros) {
  __shared__ __align__(16) unsigned short acts[352 * 64];  // 45056 B => 3 blk/CU
  int tid = threadIdx.x;
  int lane = tid & 63, wave = tid >> 6;                    // 8 waves
  int logical = xcd_swz(blockIdx.x, 128);
  int tilex = logical & 15, tiley = logical >> 4;
  int c0 = tilex * 32, r0 = tiley * 8;

  // acts halo staging (344 used px, padded 352)
  for (int wi = wave; wi < 44; wi += 8) {
    int cidx = wi * 64 + lane;
    int pix = cidx >> 3, slotp = cidx & 7;
    int prow = pix / 34, pcol = pix - prow * 34;
    int gr = r0 + prow - 1, gc = c0 + pcol - 1;
    int slot = slotp ^ (pix & 7);
    bool ok = (pix < 340) & ((unsigned)gr < 512u) & ((unsigned)gc < 512u);
    const unsigned short* src = ok ? (xin + (((size_t)(gr * 512 + gc)) << 6) + slot * 8) : zeros;
    unsigned short* dstb = &acts[wi * 512];  // wave-uniform base
    __builtin_amdgcn_global_load_lds((const __attribute__((address_space(1))) void*)src,
                                     (__attribute__((address_space(3))) void*)dstb, 16, 0, 0);
  }
  __syncthreads();

  int q = lane >> 4, n = lane & 15;
  f32x4 acc[2];
#pragma unroll
  for (int g = 0; g < 2; ++g) acc[g] = (f32x4){0.f, 0.f, 0.f, 0.f};
  int plbase[2];
#pragma unroll
  for (int g = 0; g < 2; ++g) plbase[g] = wave * 34 + 16 * g + n;
  const char* actb = (const char*)acts;

#pragma unroll
  for (int k = 0; k < 18; ++k) {                           // no barriers
    const int tap = k >> 1, kc = k & 1;
    const int kyy = tap / 3, kxx = tap - kyy * 3;
    short8 af = *reinterpret_cast<const short8*>(wts + (size_t)k * 512 + n * 32 + q * 8);
#pragma unroll
    for (int g = 0; g < 2; ++g) {
      int pl = plbase[g] + kyy * 34 + kxx;
      int addr = pl * 128 + (((kc * 4 + q) ^ (pl & 7)) * 16);
      short8 bf = *reinterpret_cast<const short8*>(actb + addr);
      acc[g] = __builtin_amdgcn_mfma_f32_16x16x32_bf16(af, bf, acc[g], 0, 0, 0);
    }
  }

  // ---- epilogue: acc -> bf16 in LDS (24B/px rows) -> coalesced 4B copies ----
  __syncthreads();
  char* ob = (char*)acts;
  float bb[4];
#pragma unroll
  for (int r2 = 0; r2 < 4; ++r2) {
    int oc = q * 4 + r2;
    bb[r2] = (oc < 10) ? bias[oc] : 0.f;
  }
#pragma unroll
  for (int g = 0; g < 2; ++g) {
    int pl = wave * 32 + g * 16 + n;
    f32x4 v = acc[g];
    float o0 = v.x + bb[0], o1 = v.y + bb[1], o2 = v.z + bb[2], o3 = v.w + bb[3];
    if (q < 2) {
      unsigned u0 = (unsigned)f2bf(o0) | ((unsigned)f2bf(o1) << 16);
      unsigned u1 = (unsigned)f2bf(o2) | ((unsigned)f2bf(o3) << 16);
      *reinterpret_cast<uint2*>(ob + pl * 24 + q * 8) = make_uint2(u0, u1);
    } else if (q == 2) {
      *reinterpret_cast<unsigned*>(ob + pl * 24 + 16) =
          (unsigned)f2bf(o0) | ((unsigned)f2bf(o1) << 16);
    }
  }
  __syncthreads();
  char* fb = (char*)feats;
#pragma unroll
  for (int it = 0; it < 3; ++it) {
    int c = it * 512 + tid;                            // 1280 4-B words (8 rows x 640 B)
    if (c < 1280) {
      int row = c / 160, wb = c - row * 160;
      int byte = wb * 4;
      int px = byte / 20, off = byte - px * 20;
      unsigned v = *reinterpret_cast<const unsigned*>(ob + (row * 32 + px) * 24 + off);
      size_t gbyte = (((size_t)(r0 + row) * 512) + c0) * 20 + (size_t)byte;
      *reinterpret_cast<unsigned*>(fb + gbyte) = v;
    }
  }
}

// ---------------- scatter: LDS accumulate -> per-block partials (bf16 feats); 512 thr ----------------
__global__ __launch_bounds__(512) void scatter_k(const unsigned short* __restrict__ feats,
                                                 const int* __restrict__ pix_rc,
                                                 const int* __restrict__ seg,
                                                 float* __restrict__ partials) {
  __shared__ float ls[NSP * 10];
  __shared__ float lc[NSP];
  int tid = threadIdx.x;
  for (int i = tid; i < NSP * 10; i += 512) ls[i] = 0.f;
  for (int i = tid; i < NSP; i += 512) lc[i] = 0.f;
  __syncthreads();

  constexpr int PER = P / SBLK;  // 512
  int p0 = blockIdx.x * PER;
  for (int p = p0 + tid; p < p0 + PER; p += 512) {
    int2 rc = *reinterpret_cast<const int2*>(pix_rc + 2 * p);
    int s = seg[p];
    size_t gpix = (size_t)rc.x * 512 + rc.y;
    const char* fp = (const char*)feats + gpix * 20;
    uint4 a = *reinterpret_cast<const uint4*>(fp);       // 16 B (4-aligned)
    unsigned e = *reinterpret_cast<const unsigned*>(fp + 16);
    float v[10];
    v[0] = bflo(a.x); v[1] = bfhi(a.x);
    v[2] = bflo(a.y); v[3] = bfhi(a.y);
    v[4] = bflo(a.z); v[5] = bfhi(a.z);
    v[6] = bflo(a.w); v[7] = bfhi(a.w);
    v[8] = bflo(e);   v[9] = bfhi(e);
#pragma unroll
    for (int ch = 0; ch < 10; ++ch) atomicAdd(&ls[s * 10 + ch], v[ch]);
    atomicAdd(&lc[s], 1.f);
  }
  __syncthreads();

  float* outp = partials + (size_t)blockIdx.x * (NSP * 11);
  for (int i = tid; i < NSP * 10; i += 512) outp[i] = ls[i];
  for (int i = tid; i < NSP; i += 512) outp[NSP * 10 + i] = lc[i];
}

// ---------------- finalize stage A: 16 groups x 32 sets -> partials2 ----------------
__global__ __launch_bounds__(256) void finA_k(const float* __restrict__ partials,
                                              float* __restrict__ partials2) {
  int g = blockIdx.x / 44;                        // 44 blocks/group (44*256 = 11264)
  int e = (blockIdx.x - g * 44) * 256 + threadIdx.x;
  const float* base = partials + (size_t)(g * 32) * (NSP * 11) + e;
  float s = 0.f;
#pragma unroll 8
  for (int k = 0; k < 32; ++k) s += base[(size_t)k * (NSP * 11)];
  partials2[(size_t)g * (NSP * 11) + e] = s;
}

// ---------------- finalize stage B: sum 16 groups, divide ----------------
__global__ __launch_bounds__(256) void finB_k(const float* __restrict__ partials2,
                                              float* __restrict__ out) {
  int i = blockIdx.x * 256 + threadIdx.x;
  if (i >= NSP * 10) return;
  int sp = i / 10;
  float s = 0.f, cnt = 0.f;
#pragma unroll
  for (int g = 0; g < FGRP; ++g) {
    const float* pp = partials2 + (size_t)g * (NSP * 11);
    s += pp[i];
    cnt += pp[NSP * 10 + sp];
  }
  out[i] = s / fmaxf(cnt, 1.f);
}

extern "C" void kernel_launch(void* const* d_in, const int* in_sizes, int n_in,
                              void* d_out, int out_size, void* d_ws, size_t ws_size,
                              hipStream_t stream) {
  const float* raw = (const float*)d_in[0];
  const float* w1  = (const float*)d_in[1];
  const float* b1  = (const float*)d_in[2];
  const float* w2  = (const float*)d_in[3];
  const float* b2  = (const float*)d_in[4];
  const float* w3  = (const float*)d_in[5];
  const float* b3  = (const float*)d_in[6];
  const int* pix_rc = (const int*)d_in[7];
  const int* seg    = (const int*)d_in[8];
  float* out = (float*)d_out;

  char* ws = (char*)d_ws;
  float* partials  = (float*)(ws + 0);                       // 512 * 11264 f32 = 23.07 MB
  float* partials2 = (float*)(ws + 23068672);                // 16 * 11264 f32 = 0.72 MB
  unsigned short* h2    = (unsigned short*)(ws + 25165824);  // [P][64] bf16, 33.55 MB
  unsigned short* feats = (unsigned short*)(ws + 58720256);  // [P][10] bf16, 5.25 MB
  unsigned short* wt2s  = (unsigned short*)(ws + 63963136);  // 36864 shorts = 73728 B
  unsigned short* wt3s  = (unsigned short*)(ws + 64036864);  // 9216 shorts = 18432 B
  unsigned short* zeros = (unsigned short*)(ws + 64055296);  // 256 B zero stub

  prep_k<<<180, 256, 0, stream>>>(w2, w3, wt2s, wt3s, zeros);
  conv2_k<<<1024, 512, 0, stream>>>(raw, w1, b1, wt2s, b2, h2);
  conv3_k<<<1024, 512, 0, stream>>>(h2, wt3s, b3, feats, zeros);
  scatter_k<<<SBLK, 512, 0, stream>>>(feats, pix_rc, seg, partials);
  finA_k<<<FGRP * 44, 256, 0, stream>>>(partials, partials2);
  finB_k<<<40, 256, 0, stream>>>(partials2, out);
}

// Round 20
// 80.118 us; speedup vs baseline: 1.2635x; 1.2635x over previous
//
#include <hip/hip_runtime.h>

typedef __attribute__((ext_vector_type(8))) short short8;
typedef __attribute__((ext_vector_type(4))) float f32x4;

constexpr int H = 512, W = 512;
constexpr int P = H * W;     // 262144
constexpr int NSP = 1024;
constexpr int SBLK = 512;    // scatter partial sets
constexpr int FGRP = 16;     // finalize stage-A groups (32 sets each)

__device__ inline unsigned short f2bf(float f) {
  unsigned u = __builtin_bit_cast(unsigned, f);
  unsigned r = (u + 0x7fffu + ((u >> 16) & 1u)) >> 16;  // RNE
  return (unsigned short)r;
}
__device__ inline float bflo(unsigned u) { return __builtin_bit_cast(float, u << 16); }
__device__ inline float bfhi(unsigned u) { return __builtin_bit_cast(float, u & 0xffff0000u); }

// XCD-band swizzle (bijective: grid % 8 == 0). cpx = grid/8.
__device__ inline int xcd_swz(int b, int cpx) { return (b & 7) * cpx + (b >> 3); }

// ---------------- prep: weights -> staged-order bf16 with baked-in swizzle ----------------
// Cell (row r, stored slot s): s = slot' ^ ((r>>2)&3); reader slot' = q ^ ((r>>2)&3).
__global__ __launch_bounds__(256) void prep_k(const float* __restrict__ w2,
                                              const float* __restrict__ w3,
                                              unsigned short* __restrict__ wt2s,
                                              unsigned short* __restrict__ wt3s,
                                              unsigned short* __restrict__ zeros) {
  if (blockIdx.x == 0 && threadIdx.x < 128) zeros[threadIdx.x] = 0;  // 256-B zero stub
  int i = blockIdx.x * 256 + threadIdx.x;
  if (i < 36864) {                     // conv2: 18 chunks x 2048 shorts (64 oc rows)
    int k = i >> 11;
    int t = (i >> 3) & 255;
    int e = i & 7;
    int r = t >> 2, sp = t & 3, s = sp ^ ((r >> 2) & 3);
    int tap = k >> 1, ic = (k & 1) * 32 + s * 8 + e;
    wt2s[i] = f2bf(w2[r * 576 + ic * 9 + tap]);
  } else if (i < 46080) {              // conv3: 18 chunks x 512 shorts (16 rows, 10 real)
    int j = i - 36864;
    int k = j >> 9;
    int t = (j >> 3) & 63;
    int e = j & 7;
    int r = t >> 2, sp = t & 3, s = sp ^ ((r >> 2) & 3);
    int tap = k >> 1, ic = (k & 1) * 32 + s * 8 + e;
    wt3s[j] = (r < 10) ? f2bf(w3[r * 576 + ic * 9 + tap]) : (unsigned short)0;
  }
}

// ---------------- conv2 (fused conv1-via-MFMA + conv2): raw -> h2 NHWC bf16; 32x8, 512 thr ----------------
// Phase 2 ring: 9 rounds x one full tap (8 KB = kc 0,1), 3-slot ring, 16 MFMA/round.
__global__ __launch_bounds__(512) void conv2_k(const float* __restrict__ raw,
                                               const float* __restrict__ w1,
                                               const float* __restrict__ b1,
                                               const unsigned short* __restrict__ wts,
                                               const float* __restrict__ bias,
                                               unsigned short* __restrict__ ynhwc) {
  constexpr int DCS = 4096;                                // double-chunk shorts (8 KiB = 1 tap)
  __shared__ __align__(16) unsigned short acts[352 * 64];  // 45056 B
  __shared__ __align__(16) unsigned short wbuf[3 * DCS];   // 24576 B (3-slot ring)
  __shared__ unsigned short rawtb[12 * 36 + 4];            // 872 B => 70504 B, 2 blk/CU
  int tid = threadIdx.x;
  int lane = tid & 63, wave = tid >> 6;                    // 8 waves
  int logical = xcd_swz(blockIdx.x, 128);
  int tilex = logical & 15, tiley = logical >> 4;
  int c0 = tilex * 32, r0 = tiley * 8;

  // ---- weight prologue: taps 0,1 (all 512 threads, 16B each = 8 KB/tap) ----
#pragma unroll
  for (int k0 = 0; k0 < 2; ++k0) {
    const unsigned short* src = wts + (size_t)k0 * DCS + tid * 8;
    unsigned short* dstb = wbuf + k0 * DCS + wave * 512;
    __builtin_amdgcn_global_load_lds((const __attribute__((address_space(1))) void*)src,
                                     (__attribute__((address_space(3))) void*)dstb, 16, 0, 0);
  }
  // ---- stage raw halo-of-halo [12 rows][36 cols] (rows r0-2 .. r0+9) as bf16 ----
  if (tid < 432) {
    int rr = tid / 36, cc = tid - rr * 36;
    int gr = r0 + rr - 2, gc = c0 + cc - 2;
    bool ok = ((unsigned)gr < 512u) && ((unsigned)gc < 512u);
    rawtb[tid] = ok ? f2bf(raw[gr * 512 + gc]) : (unsigned short)0;
  }

  int q = lane >> 4, n = lane & 15;
  int og1 = wave & 3;
  // A-frag for conv1: row = oc (og1*16+n), k = q*8+e; taps 0-8 real, rest 0.
  short8 a1f;
  {
    short av[8];
#pragma unroll
    for (int e = 0; e < 8; ++e) av[e] = 0;
    int oc = og1 * 16 + n;
    if (q == 0) {
#pragma unroll
      for (int e = 0; e < 8; ++e) av[e] = (short)f2bf(w1[oc * 9 + e]);
    } else if (q == 1) {
      av[0] = (short)f2bf(w1[oc * 9 + 8]);
    }
    a1f = (short8){av[0], av[1], av[2], av[3], av[4], av[5], av[6], av[7]};
  }
  float bb1[4];
#pragma unroll
  for (int r2 = 0; r2 < 4; ++r2) bb1[r2] = b1[og1 * 16 + q * 4 + r2];
  __syncthreads();  // rawtb visible (full drain: taps 0,1 landed)

  // ---- phase 1: conv1 via MFMA; waves 0-3: t=0..10, waves 4-7: t=11..21 ----
  char* actw = (char*)acts;
  int tbase = (wave < 4) ? 0 : 11;
  for (int ti = 0; ti < 11; ++ti) {
    int t = tbase + ti;
    int px = t * 16 + n;                                 // 0..351
    bool okp = px < 340;
    int prow = px / 34, pcol = px - prow * 34;
    int prc = okp ? prow : 9;                            // clamp rawtb row for px>=340
    short bv[8];
#pragma unroll
    for (int e = 0; e < 8; ++e) bv[e] = 0;
    if (q == 0) {
#pragma unroll
      for (int e = 0; e < 8; ++e) {
        int dy = e / 3, dx = e - dy * 3;                 // taps 0..7
        bv[e] = (short)rawtb[(prc + dy) * 36 + pcol + dx];
      }
    } else if (q == 1) {
      bv[0] = (short)rawtb[(prc + 2) * 36 + pcol + 2];   // tap 8
    }
    short8 b1f = (short8){bv[0], bv[1], bv[2], bv[3], bv[4], bv[5], bv[6], bv[7]};
    f32x4 d = __builtin_amdgcn_mfma_f32_16x16x32_bf16(a1f, b1f,
                                                       (f32x4){0.f, 0.f, 0.f, 0.f}, 0, 0, 0);
    int gr1 = r0 + prow - 1, gc1 = c0 + pcol - 1;
    bool ok1 = okp && ((unsigned)gr1 < 512u) && ((unsigned)gc1 < 512u);
    float o0 = ok1 ? fmaxf(d.x + bb1[0], 0.f) : 0.f;
    float o1 = ok1 ? fmaxf(d.y + bb1[1], 0.f) : 0.f;
    float o2 = ok1 ? fmaxf(d.z + bb1[2], 0.f) : 0.f;
    float o3 = ok1 ? fmaxf(d.w + bb1[3], 0.f) : 0.f;
    unsigned lo = (unsigned)f2bf(o0) | ((unsigned)f2bf(o1) << 16);
    unsigned hi = (unsigned)f2bf(o2) | ((unsigned)f2bf(o3) << 16);
    int wa = px * 128 + ((((og1 * 2 + (q >> 1)) ^ (px & 7)) << 4)) + ((q & 1) << 3);
    *reinterpret_cast<uint2*>(actw + wa) = make_uint2(lo, hi);
  }
  __syncthreads();  // acts complete; full drain — ring bookkeeping starts clean

  // ---- phase 2: 9-round tap ring (3 slots, issue j+2 after barrier) ----
  f32x4 acc[4][2];
#pragma unroll
  for (int og = 0; og < 4; ++og)
#pragma unroll
    for (int g = 0; g < 2; ++g) acc[og][g] = (f32x4){0.f, 0.f, 0.f, 0.f};

  int plbase[2];
#pragma unroll
  for (int g = 0; g < 2; ++g) plbase[g] = wave * 34 + 16 * g + n;
  const char* actb = (const char*)acts;

#pragma unroll
  for (int j = 0; j < 9; ++j) {
    if (j == 8) {
      asm volatile("s_waitcnt vmcnt(0)" ::: "memory");  // tap 8 landed
    } else {
      asm volatile("s_waitcnt vmcnt(1)" ::: "memory");  // tap j landed (j+1 may fly)
    }
    __builtin_amdgcn_sched_barrier(0);
    __builtin_amdgcn_s_barrier();                      // all parts landed; NO drain
    __builtin_amdgcn_sched_barrier(0);
    if (j + 2 < 9) {                                   // slot (j+2)%3: readers done at j-1
      const unsigned short* src = wts + (size_t)(j + 2) * DCS + tid * 8;
      unsigned short* dstb = wbuf + ((j + 2) % 3) * DCS + wave * 512;
      __builtin_amdgcn_global_load_lds((const __attribute__((address_space(1))) void*)src,
                                       (__attribute__((address_space(3))) void*)dstb, 16, 0, 0);
    }
    const int kyy = j / 3, kxx = j - kyy * 3;
    const char* sb = (const char*)(wbuf + (j % 3) * DCS);
#pragma unroll
    for (int kc = 0; kc < 2; ++kc) {
      const char* wb = sb + kc * 4096;
      short8 af[4];
#pragma unroll
      for (int og = 0; og < 4; ++og) {
        int r = og * 16 + n;
        af[og] = *reinterpret_cast<const short8*>(wb + r * 64 + ((q ^ ((r >> 2) & 3)) * 16));
      }
#pragma unroll
      for (int g = 0; g < 2; ++g) {
        int pl = plbase[g] + kyy * 34 + kxx;
        int addr = pl * 128 + (((kc * 4 + q) ^ (pl & 7)) * 16);
        short8 bf = *reinterpret_cast<const short8*>(actb + addr);
#pragma unroll
        for (int og = 0; og < 4; ++og)
          acc[og][g] = __builtin_amdgcn_mfma_f32_16x16x32_bf16(af[og], bf, acc[og][g], 0, 0, 0);
      }
    }
  }

  // ---- epilogue: acc -> LDS (swizzled NHWC tile, 256 px) -> coalesced 16B stores ----
  __syncthreads();  // acts reads done; safe to reuse as output staging
  char* ob = (char*)acts;
#pragma unroll
  for (int og = 0; og < 4; ++og) {
    float b0 = bias[og * 16 + q * 4 + 0], b1v = bias[og * 16 + q * 4 + 1];
    float b2 = bias[og * 16 + q * 4 + 2], b3 = bias[og * 16 + q * 4 + 3];
#pragma unroll
    for (int g = 0; g < 2; ++g) {
      int pl = wave * 32 + g * 16 + n;
      f32x4 v = acc[og][g];
      float o0 = fmaxf(v.x + b0, 0.f), o1 = fmaxf(v.y + b1v, 0.f);
      float o2 = fmaxf(v.z + b2, 0.f), o3 = fmaxf(v.w + b3, 0.f);
      unsigned lo = (unsigned)f2bf(o0) | ((unsigned)f2bf(o1) << 16);
      unsigned hi = (unsigned)f2bf(o2) | ((unsigned)f2bf(o3) << 16);
      int lslot = og * 2 + (q >> 1);                   // logical 16B slot
      int wa = pl * 128 + (((lslot ^ (pl & 7)) << 4)) + ((q & 1) << 3);
      *reinterpret_cast<uint2*>(ob + wa) = make_uint2(lo, hi);
    }
  }
  __syncthreads();
  char* yb = (char*)ynhwc;
#pragma unroll
  for (int it = 0; it < 4; ++it) {
    int c = it * 512 + tid;                            // 2048 16-B chunks
    int pl = c >> 3, slot = c & 7;
    uint4 v = *reinterpret_cast<const uint4*>(ob + pl * 128 + ((slot ^ (pl & 7)) << 4));
    size_t gb = (((size_t)(r0 + (pl >> 5)) * 512) + c0 + (pl & 31)) * 128 + slot * 16;
    *reinterpret_cast<uint4*>(yb + gb) = v;
  }
}

// ---------------- conv3 (MFMA): 64 -> 10, NHWC bf16 out; 32x8 tile, 512 thr ----------------
__global__ __launch_bounds__(512) void conv3_k(const unsigned short* __restrict__ xin,
                                               const unsigned short* __restrict__ wts,
                                               const float* __restrict__ bias,
                                               unsigned short* __restrict__ feats,
                                               const unsigned short* __restrict__ zeros) {
  __shared__ __align__(16) unsigned short acts[352 * 64];  // 45056 B
  __shared__ __align__(16) unsigned short wl[9216];        // 18432 B => 63488 B, 2 blk/CU
  int tid = threadIdx.x;
  int lane = tid & 63, wave = tid >> 6;                    // 8 waves
  int logical = xcd_swz(blockIdx.x, 128);
  int tilex = logical & 15, tiley = logical >> 4;
  int c0 = tilex * 32, r0 = tiley * 8;

  // weights first (needed at k=0), then acts halo (344 used px, padded 352)
  for (int wi = wave; wi < 18; wi += 8) {
    const unsigned short* src = wts + (size_t)wi * 512 + lane * 8;
    unsigned short* dstb = &wl[wi * 512];
    __builtin_amdgcn_global_load_lds((const __attribute__((address_space(1))) void*)src,
                                     (__attribute__((address_space(3))) void*)dstb, 16, 0, 0);
  }
  for (int wi = wave; wi < 44; wi += 8) {
    int cidx = wi * 64 + lane;
    int pix = cidx >> 3, slotp = cidx & 7;
    int prow = pix / 34, pcol = pix - prow * 34;
    int gr = r0 + prow - 1, gc = c0 + pcol - 1;
    int slot = slotp ^ (pix & 7);
    bool ok = (pix < 340) & ((unsigned)gr < 512u) & ((unsigned)gc < 512u);
    const unsigned short* src = ok ? (xin + (((size_t)(gr * 512 + gc)) << 6) + slot * 8) : zeros;
    unsigned short* dstb = &acts[wi * 512];  // wave-uniform base
    __builtin_amdgcn_global_load_lds((const __attribute__((address_space(1))) void*)src,
                                     (__attribute__((address_space(3))) void*)dstb, 16, 0, 0);
  }
  __syncthreads();

  int q = lane >> 4, n = lane & 15;
  f32x4 acc[2];
#pragma unroll
  for (int g = 0; g < 2; ++g) acc[g] = (f32x4){0.f, 0.f, 0.f, 0.f};
  int plbase[2];
#pragma unroll
  for (int g = 0; g < 2; ++g) plbase[g] = wave * 34 + 16 * g + n;
  const char* actb = (const char*)acts;
  const char* wb0 = (const char*)wl;

#pragma unroll
  for (int k = 0; k < 18; ++k) {                           // no barriers, no waitcnts
    const int tap = k >> 1, kc = k & 1;
    const int kyy = tap / 3, kxx = tap - kyy * 3;
    short8 af = *reinterpret_cast<const short8*>(wb0 + k * 1024 + n * 64 +
                                                 ((q ^ ((n >> 2) & 3)) * 16));
#pragma unroll
    for (int g = 0; g < 2; ++g) {
      int pl = plbase[g] + kyy * 34 + kxx;
      int addr = pl * 128 + (((kc * 4 + q) ^ (pl & 7)) * 16);
      short8 bf = *reinterpret_cast<const short8*>(actb + addr);
      acc[g] = __builtin_amdgcn_mfma_f32_16x16x32_bf16(af, bf, acc[g], 0, 0, 0);
    }
  }

  // ---- epilogue: acc -> bf16 in LDS (24B/px rows) -> coalesced 4B copies ----
  __syncthreads();
  char* ob = (char*)acts;
  float bb[4];
#pragma unroll
  for (int r2 = 0; r2 < 4; ++r2) {
    int oc = q * 4 + r2;
    bb[r2] = (oc < 10) ? bias[oc] : 0.f;
  }
#pragma unroll
  for (int g = 0; g < 2; ++g) {
    int pl = wave * 32 + g * 16 + n;
    f32x4 v = acc[g];
    float o0 = v.x + bb[0], o1 = v.y + bb[1], o2 = v.z + bb[2], o3 = v.w + bb[3];
    if (q < 2) {
      unsigned u0 = (unsigned)f2bf(o0) | ((unsigned)f2bf(o1) << 16);
      unsigned u1 = (unsigned)f2bf(o2) | ((unsigned)f2bf(o3) << 16);
      *reinterpret_cast<uint2*>(ob + pl * 24 + q * 8) = make_uint2(u0, u1);
    } else if (q == 2) {
      *reinterpret_cast<unsigned*>(ob + pl * 24 + 16) =
          (unsigned)f2bf(o0) | ((unsigned)f2bf(o1) << 16);
    }
  }
  __syncthreads();
  char* fb = (char*)feats;
#pragma unroll
  for (int it = 0; it < 3; ++it) {
    int c = it * 512 + tid;                            // 1280 4-B words (8 rows x 640 B)
    if (c < 1280) {
      int row = c / 160, wb = c - row * 160;
      int byte = wb * 4;
      int px = byte / 20, off = byte - px * 20;
      unsigned v = *reinterpret_cast<const unsigned*>(ob + (row * 32 + px) * 24 + off);
      size_t gbyte = (((size_t)(r0 + row) * 512) + c0) * 20 + (size_t)byte;
      *reinterpret_cast<unsigned*>(fb + gbyte) = v;
    }
  }
}

// ---------------- scatter: LDS accumulate -> per-block partials (bf16 feats); 512 thr ----------------
__global__ __launch_bounds__(512) void scatter_k(const unsigned short* __restrict__ feats,
                                                 const int* __restrict__ pix_rc,
                                                 const int* __restrict__ seg,
                                                 float* __restrict__ partials) {
  __shared__ float ls[NSP * 10];
  __shared__ float lc[NSP];
  int tid = threadIdx.x;
  for (int i = tid; i < NSP * 10; i += 512) ls[i] = 0.f;
  for (int i = tid; i < NSP; i += 512) lc[i] = 0.f;
  __syncthreads();

  constexpr int PER = P / SBLK;  // 512
  int p0 = blockIdx.x * PER;
  for (int p = p0 + tid; p < p0 + PER; p += 512) {
    int2 rc = *reinterpret_cast<const int2*>(pix_rc + 2 * p);
    int s = seg[p];
    size_t gpix = (size_t)rc.x * 512 + rc.y;
    const char* fp = (const char*)feats + gpix * 20;
    uint4 a = *reinterpret_cast<const uint4*>(fp);       // 16 B (4-aligned)
    unsigned e = *reinterpret_cast<const unsigned*>(fp + 16);
    float v[10];
    v[0] = bflo(a.x); v[1] = bfhi(a.x);
    v[2] = bflo(a.y); v[3] = bfhi(a.y);
    v[4] = bflo(a.z); v[5] = bfhi(a.z);
    v[6] = bflo(a.w); v[7] = bfhi(a.w);
    v[8] = bflo(e);   v[9] = bfhi(e);
#pragma unroll
    for (int ch = 0; ch < 10; ++ch) atomicAdd(&ls[s * 10 + ch], v[ch]);
    atomicAdd(&lc[s], 1.f);
  }
  __syncthreads();

  float* outp = partials + (size_t)blockIdx.x * (NSP * 11);
  for (int i = tid; i < NSP * 10; i += 512) outp[i] = ls[i];
  for (int i = tid; i < NSP; i += 512) outp[NSP * 10 + i] = lc[i];
}

// ---------------- finalize stage A: 16 groups x 32 sets -> partials2 ----------------
__global__ __launch_bounds__(256) void finA_k(const float* __restrict__ partials,
                                              float* __restrict__ partials2) {
  int g = blockIdx.x / 44;                        // 44 blocks/group (44*256 = 11264)
  int e = (blockIdx.x - g * 44) * 256 + threadIdx.x;
  const float* base = partials + (size_t)(g * 32) * (NSP * 11) + e;
  float s = 0.f;
#pragma unroll 8
  for (int k = 0; k < 32; ++k) s += base[(size_t)k * (NSP * 11)];
  partials2[(size_t)g * (NSP * 11) + e] = s;
}

// ---------------- finalize stage B: sum 16 groups, divide ----------------
__global__ __launch_bounds__(256) void finB_k(const float* __restrict__ partials2,
                                              float* __restrict__ out) {
  int i = blockIdx.x * 256 + threadIdx.x;
  if (i >= NSP * 10) return;
  int sp = i / 10;
  float s = 0.f, cnt = 0.f;
#pragma unroll
  for (int g = 0; g < FGRP; ++g) {
    const float* pp = partials2 + (size_t)g * (NSP * 11);
    s += pp[i];
    cnt += pp[NSP * 10 + sp];
  }
  out[i] = s / fmaxf(cnt, 1.f);
}

extern "C" void kernel_launch(void* const* d_in, const int* in_sizes, int n_in,
                              void* d_out, int out_size, void* d_ws, size_t ws_size,
                              hipStream_t stream) {
  const float* raw = (const float*)d_in[0];
  const float* w1  = (const float*)d_in[1];
  const float* b1  = (const float*)d_in[2];
  const float* w2  = (const float*)d_in[3];
  const float* b2  = (const float*)d_in[4];
  const float* w3  = (const float*)d_in[5];
  const float* b3  = (const float*)d_in[6];
  const int* pix_rc = (const int*)d_in[7];
  const int* seg    = (const int*)d_in[8];
  float* out = (float*)d_out;

  char* ws = (char*)d_ws;
  float* partials  = (float*)(ws + 0);                       // 512 * 11264 f32 = 23.07 MB
  float* partials2 = (float*)(ws + 23068672);                // 16 * 11264 f32 = 0.72 MB
  unsigned short* h2    = (unsigned short*)(ws + 25165824);  // [P][64] bf16, 33.55 MB
  unsigned short* feats = (unsigned short*)(ws + 58720256);  // [P][10] bf16, 5.25 MB
  unsigned short* wt2s  = (unsigned short*)(ws + 63963136);  // 36864 shorts = 73728 B
  unsigned short* wt3s  = (unsigned short*)(ws + 64036864);  // 9216 shorts = 18432 B
  unsigned short* zeros = (unsigned short*)(ws + 64055296);  // 256 B zero stub

  prep_k<<<180, 256, 0, stream>>>(w2, w3, wt2s, wt3s, zeros);
  conv2_k<<<1024, 512, 0, stream>>>(raw, w1, b1, wt2s, b2, h2);
  conv3_k<<<1024, 512, 0, stream>>>(h2, wt3s, b3, feats, zeros);
  scatter_k<<<SBLK, 512, 0, stream>>>(feats, pix_rc, seg, partials);
  finA_k<<<FGRP * 44, 256, 0, stream>>>(partials, partials2);
  finB_k<<<40, 256, 0, stream>>>(partials2, out);
}